// Round 19
// baseline (80.385 us; speedup 1.0000x reference)
//
#include <hip/hip_runtime.h>
#include <math.h>

// ---------------------------------------------------------------------------
// Fused MoE top-2 router, MI355X (gfx950) — round 19: phase-split pass1.
// Theory: R14/R18's pass1 read x in 256B granules at 16KB stride (poor DRAM
// row locality, ~60% of fair-share BW). R19 block = 16 tokens x full 1024-k
// quarter: phase 1 reads x as 4KB-contiguous token segments (coalesced),
// converts fp32->bf16 hi/lo in registers, stores frag-major to LDS (XOR
// tok^(kstep&15) anti-bank-alias). Phase 2 is BARRIER-FREE: A-frags from
// LDS, B-frags straight from the L2-resident frag array (no W staging).
// 8 waves = 4 ntiles x 2 k-halves; one LDS reduction; slab/pass2/fused
// finalize unchanged from R18 (proven). LDS 68KB -> 2 blocks/CU.
// ---------------------------------------------------------------------------

#define NT 8192
#define ND 4096
#define NE 64
#define W_OFF 512         // float idx: wh (512KB)
#define WL_OFF (W_OFF + 131072)
#define SLAB2 (W_OFF + 262144)
#define BKD 64            // fallback chunk
#define SLAB_OFF 512      // fallback slab base

typedef float f32x4 __attribute__((ext_vector_type(4)));
typedef short s16x8 __attribute__((ext_vector_type(8)));
typedef short s16x4 __attribute__((ext_vector_type(4)));

__device__ __forceinline__ void gload16(const float* g, float* l) {
    __builtin_amdgcn_global_load_lds(
        (const __attribute__((address_space(1))) void*)g,
        (__attribute__((address_space(3))) void*)l, 16, 0, 0);
}

// ---- W pre-convert: fp32 -> bf16 hi/lo, fragment-major (R18 verbatim) -----
__global__ __launch_bounds__(256)
void convert_w(const float* __restrict__ W, float* __restrict__ ws)
{
    if (blockIdx.x == 0 && threadIdx.x < 131) ws[threadIdx.x] = 0.f;

    const int s = blockIdx.x * 256 + threadIdx.x;   // frag slot 0..32767
    const int sg  = s >> 8;          // kstep
    const int nt  = (s >> 6) & 3;    // n-tile
    const int kb  = (s >> 4) & 3;    // k-block (lane>>4)
    const int e15 = s & 15;
    const int e   = nt * 16 + e15;
    const int k0  = sg * 32 + kb * 8;
    const float* wr = W + (size_t)e * ND + k0;

    union { s16x8 v; ushort u[8]; } h, l;
    #pragma unroll
    for (int j = 0; j < 8; j++) {
        const float v = wr[j];
        const unsigned ub = __float_as_uint(v);
        h.u[j] = (ushort)(ub >> 16);
        const float lo = v - __uint_as_float(ub & 0xffff0000u);
        l.u[j] = (ushort)(__float_as_uint(lo) >> 16);
    }
    *(s16x8*)((ushort*)(ws + W_OFF) + (size_t)s * 8) = h.v;
    *(s16x8*)((ushort*)(ws + WL_OFF) + (size_t)s * 8) = l.v;
}

// ---- primary: phase-split pass1, kq=4, 2048 blocks x 512 thr --------------
__global__ __launch_bounds__(512, 2)
void pass1_ph(const float* __restrict__ x, float* __restrict__ ws)
{
    __shared__ ushort xh[16384];    // 32 KB: [kstep 32][slot 64][8]
    __shared__ ushort xl[16384];    // 32 KB
    __shared__ float  red[4][64][4]; // 4 KB  cross-khalf reduction

    const int tid  = threadIdx.x;
    const int bq   = blockIdx.x >> 9;      // k-quarter 0..3
    const int tb   = blockIdx.x & 511;     // token block (16 tokens)
    const int tok0 = tb * 16;
    const int k0   = bq << 10;

    // ---------------- phase 1: x -> bf16 hi/lo frags in LDS ----------------
    {
        const int tok = tid >> 5;          // 0..15
        const int s4  = tid & 31;          // 128B segment-slot
        const float* xrow = x + (size_t)(tok0 + tok) * ND + k0;
        f32x4 vx[8];
        #pragma unroll
        for (int j = 0; j < 8; j++)
            vx[j] = *(const f32x4*)(xrow + s4 * 4 + j * 128);   // coalesced 512B/instr

        const int kbw  = (s4 >> 1) & 3;    // k-block within kstep
        const int half = s4 & 1;           // which 4-of-8 in the slot
        #pragma unroll
        for (int j = 0; j < 8; j++) {
            const int kstep = (s4 >> 3) + j * 4;
            const int tokX  = tok ^ (kstep & 15);
            const int base  = (kstep * 64 + kbw * 16 + tokX) * 8 + half * 4;
            union { s16x4 v; ushort u[4]; } hh, ll;
            #pragma unroll
            for (int i = 0; i < 4; i++) {
                const float v = vx[j][i];
                const unsigned ub = __float_as_uint(v);
                hh.u[i] = (ushort)(ub >> 16);
                const float lo = v - __uint_as_float(ub & 0xffff0000u);
                ll.u[i] = (ushort)(__float_as_uint(lo) >> 16);
            }
            *(s16x4*)(xh + base) = hh.v;
            *(s16x4*)(xl + base) = ll.v;
        }
    }
    __syncthreads();                       // the ONLY pre-reduction barrier

    // ---------------- phase 2: barrier-free MFMA over 16 ksteps ------------
    const int wv   = tid >> 6, lane = tid & 63;
    const int nt   = wv & 3;               // expert tile
    const int kh   = wv >> 2;              // k half
    const int kb   = lane >> 4;
    const int tokX0 = lane & 15;

    const ushort* bb_h = (const ushort*)(ws + W_OFF)
        + ((size_t)(bq * 32) * 256 + nt * 64 + kb * 16 + (lane & 15)) * 8;
    const ushort* bb_l = (const ushort*)(ws + WL_OFF)
        + ((size_t)(bq * 32) * 256 + nt * 64 + kb * 16 + (lane & 15)) * 8;

    f32x4 acc0 = {0.f, 0.f, 0.f, 0.f};

    #pragma unroll 1
    for (int c = kh * 16; c < kh * 16 + 16; ++c) {
        const int aidx = (c * 64 + kb * 16 + (tokX0 ^ (c & 15))) * 8;
        const s16x8 ah = *(const s16x8*)(xh + aidx);
        const s16x8 al = *(const s16x8*)(xl + aidx);
        const s16x8 bh = *(const s16x8*)(bb_h + (size_t)c * 2048);
        const s16x8 bl = *(const s16x8*)(bb_l + (size_t)c * 2048);
        acc0 = __builtin_amdgcn_mfma_f32_16x16x32_bf16(ah, bh, acc0, 0, 0, 0);
        acc0 = __builtin_amdgcn_mfma_f32_16x16x32_bf16(al, bh, acc0, 0, 0, 0);
        acc0 = __builtin_amdgcn_mfma_f32_16x16x32_bf16(ah, bl, acc0, 0, 0, 0);
    }

    // ---------------- cross-khalf reduction + slab write -------------------
    if (kh == 1) {
        red[nt][lane][0] = acc0[0]; red[nt][lane][1] = acc0[1];
        red[nt][lane][2] = acc0[2]; red[nt][lane][3] = acc0[3];
    }
    __syncthreads();
    if (kh == 0) {
        float* slab = ws + SLAB2 + (size_t)bq * NT * NE;
        const int er = (lane >> 4) * 4;
        #pragma unroll
        for (int r = 0; r < 4; r++) {
            const int token = tok0 + er + r;
            slab[(size_t)token * NE + nt * 16 + (lane & 15)] =
                acc0[r] + red[nt][lane][r];
        }
    }
}

// ---- fallback: R8 VALU double-buffer path (only if ws tiny) ---------------
#define LOADX(dst, off)                                                      \
    {                                                                        \
        _Pragma("unroll")                                                    \
        for (int t = 0; t < 8; t++)                                          \
            dst[t] = *reinterpret_cast<const float4*>(                       \
                xp + (size_t)t * ND + (off));                                \
    }
#define COMP(xv, wptr, wstride)                                              \
    {                                                                        \
        float4 wvv[8];                                                       \
        _Pragma("unroll")                                                    \
        for (int e = 0; e < 8; e++)                                          \
            wvv[e] = *reinterpret_cast<const float4*>((wptr) + e * (wstride));\
        _Pragma("unroll")                                                    \
        for (int e = 0; e < 8; e++) {                                        \
            _Pragma("unroll")                                                \
            for (int t = 0; t < 8; t++) {                                    \
                float a = acc[t][e];                                         \
                a = fmaf(xv[t].x, wvv[e].x, a);                              \
                a = fmaf(xv[t].y, wvv[e].y, a);                              \
                a = fmaf(xv[t].z, wvv[e].z, a);                              \
                a = fmaf(xv[t].w, wvv[e].w, a);                              \
                acc[t][e] = a;                                               \
            }                                                                \
        }                                                                    \
    }

__global__ __launch_bounds__(256, 2)
void pass1_dbuf(const float* __restrict__ x, const float* __restrict__ W,
                float* __restrict__ ws, int kq_bits, int nchunk)
{
    __shared__ float wbuf[2][NE * BKD];
    const int tid  = threadIdx.x;
    const int wave = tid >> 6;
    const int lane = tid & 63;
    const int eg   = lane >> 3;
    const int ks   = lane & 7;
    const int bq   = blockIdx.x >> 8;
    const int tb   = blockIdx.x & 255;
    const int tok0 = tb * 32 + wave * 8;
    const int k0   = bq * (ND >> kq_bits);

    float acc[8][8];
    #pragma unroll
    for (int t = 0; t < 8; t++)
        #pragma unroll
        for (int e = 0; e < 8; e++) acc[t][e] = 0.f;

    const float* xp = x + (size_t)tok0 * ND + k0 + ks * 4;
    #pragma unroll
    for (int r = 0; r < 4; r++) {
        int s = r * 256 + tid;
        gload16(W + (size_t)(s >> 4) * ND + k0 + (s & 15) * 4, &wbuf[0][s << 2]);
    }
    float4 xa[8], xb[8];
    LOADX(xa, 0);
    __syncthreads();

    #pragma unroll 1
    for (int c = 0; c < nchunk; ++c) {
        const int b = c & 1;
        if (c + 1 < nchunk) {
            const int koff = k0 + (c + 1) * BKD;
            #pragma unroll
            for (int r = 0; r < 4; r++) {
                int s = r * 256 + tid;
                gload16(W + (size_t)(s >> 4) * ND + koff + (s & 15) * 4,
                        &wbuf[b ^ 1][s << 2]);
            }
        }
        LOADX(xb, c * BKD + 32);
        COMP(xa, &wbuf[b][(eg * 8) * BKD + ks * 4], BKD);
        if (c + 1 < nchunk) LOADX(xa, (c + 1) * BKD);
        COMP(xb, &wbuf[b][(eg * 8) * BKD + 32 + ks * 4], BKD);
        __syncthreads();
    }

    #pragma unroll
    for (int t = 0; t < 8; t++)
        #pragma unroll
        for (int e = 0; e < 8; e++) {
            float v = acc[t][e];
            v += __shfl_xor(v, 1);
            v += __shfl_xor(v, 2);
            v += __shfl_xor(v, 4);
            acc[t][e] = v;
        }
    float* slab = ws + SLAB_OFF + ((size_t)bq * NT + tok0) * NE;
    #pragma unroll
    for (int t = 0; t < 8; t++) {
        if (ks == t) {
            *reinterpret_cast<float4*>(slab + (size_t)t * NE + eg * 8) =
                make_float4(acc[t][0], acc[t][1], acc[t][2], acc[t][3]);
            *reinterpret_cast<float4*>(slab + (size_t)t * NE + eg * 8 + 4) =
                make_float4(acc[t][4], acc[t][5], acc[t][6], acc[t][7]);
        }
    }
}

// ---- pass2 (R18 verbatim) + fused last-block finalize ----------------------
__global__ __launch_bounds__(128)
void pass2(float* __restrict__ ws, float* __restrict__ out, int kq,
           int slab_base, int nblocks, int do_fuse)
{
    __shared__ float imp_s[NE];
    __shared__ float load_s[NE];
    __shared__ int lastflag;
    const int tid  = threadIdx.x;
    const int lane = tid & 63;
    if (tid < NE) { imp_s[tid] = 0.f; load_s[tid] = 0.f; }
    __syncthreads();

    const int tok = blockIdx.x * 128 + tid;
    float lgv[NE];
    {
        const float* p0 = ws + slab_base + (size_t)tok * NE;
        #pragma unroll
        for (int e4 = 0; e4 < 16; e4++) {
            float4 v = *reinterpret_cast<const float4*>(p0 + e4 * 4);
            lgv[e4*4+0] = v.x; lgv[e4*4+1] = v.y;
            lgv[e4*4+2] = v.z; lgv[e4*4+3] = v.w;
        }
        for (int q = 1; q < kq; q++) {
            const float* pq = ws + slab_base + ((size_t)q * NT + tok) * NE;
            #pragma unroll
            for (int e4 = 0; e4 < 16; e4++) {
                float4 v = *reinterpret_cast<const float4*>(pq + e4 * 4);
                lgv[e4*4+0] += v.x; lgv[e4*4+1] += v.y;
                lgv[e4*4+2] += v.z; lgv[e4*4+3] += v.w;
            }
        }
    }

    float m = -3.0e38f;
    #pragma unroll
    for (int e = 0; e < NE; e++) m = fmaxf(m, lgv[e]);
    float se = 0.f, ssum = 0.f;
    #pragma unroll
    for (int e = 0; e < NE; e++) { ssum += lgv[e]; se += __expf(lgv[e] - m); }
    const float lse = m + __logf(se);
    const float inv = 1.f / se;

    #pragma unroll
    for (int e = 0; e < NE; e++) lgv[e] = __expf(lgv[e] - m) * inv;

    float v1 = -3.0e38f, v2 = -3.0e38f;
    int   i1 = 0, i2 = 0;
    #pragma unroll
    for (int e = 0; e < NE; e++) {
        const float v = lgv[e];
        if (v > v1)      { v2 = v1; i2 = i1; v1 = v; i1 = e; }
        else if (v > v2) { v2 = v;  i2 = e; }
    }
    const float dn = fmaxf(v1 + v2, 1e-9f);

    out[2 * tok]              = (float)i1;
    out[2 * tok + 1]          = (float)i2;
    out[2 * NT + 2 * tok]     = v1 / dn;
    out[2 * NT + 2 * tok + 1] = v2 / dn;
    atomicAdd(&load_s[i1], 1.0f);

    float zv = lse * lse, sv = ssum;
    #pragma unroll
    for (int mk = 1; mk < 64; mk <<= 1) {
        zv += __shfl_xor(zv, mk);
        sv += __shfl_xor(sv, mk);
    }
    if (lane == 0) { atomicAdd(&ws[128], zv); atomicAdd(&ws[129], sv); }

    float impacc = 0.f;
    #pragma unroll
    for (int e = 0; e < NE; e++) {
        float v = lgv[e];
        #pragma unroll
        for (int mk = 1; mk < 64; mk <<= 1) v += __shfl_xor(v, mk);
        if (lane == e) impacc = v;
    }
    atomicAdd(&imp_s[lane], impacc);

    __syncthreads();
    if (tid < NE) {
        atomicAdd(&ws[tid], imp_s[tid]);
        atomicAdd(&ws[NE + tid], load_s[tid]);
    }

    if (!do_fuse) return;

    __threadfence();
    if (tid == 0) {
        const int old = atomicAdd((int*)(ws + 130), 1);
        lastflag = (old == nblocks - 1);
    }
    __syncthreads();
    if (lastflag && tid < 64) {
        const float imp = atomicAdd(&ws[tid], 0.f);
        const float ld  = atomicAdd(&ws[NE + tid], 0.f);
        float is = imp, ls = ld;
        #pragma unroll
        for (int mk = 1; mk < 64; mk <<= 1) {
            is += __shfl_xor(is, mk);
            ls += __shfl_xor(ls, mk);
        }
        float v = (imp / fmaxf(is, 1e-9f)) * (ld / fmaxf(ls, 1e-9f));
        #pragma unroll
        for (int mk = 1; mk < 64; mk <<= 1) v += __shfl_xor(v, mk);
        if (tid == 0) {
            const float zz = atomicAdd(&ws[128], 0.f);
            const float ss = atomicAdd(&ws[129], 0.f);
            out[4 * NT]     = (zz / (float)NT) * 0.001f;
            out[4 * NT + 1] = v * (float)(NE * NE) * 0.01f;
            out[4 * NT + 2] = ss / (float)((size_t)NT * NE);
        }
    }
}

__global__ void finalize(const float* __restrict__ ws, float* __restrict__ out)
{
    const int l = threadIdx.x;
    const float imp = ws[l];
    const float ld  = ws[NE + l];
    float is = imp, ls = ld;
    #pragma unroll
    for (int mk = 1; mk < 64; mk <<= 1) { is += __shfl_xor(is, mk); ls += __shfl_xor(ls, mk); }
    float v = (imp / fmaxf(is, 1e-9f)) * (ld / fmaxf(ls, 1e-9f));
    #pragma unroll
    for (int mk = 1; mk < 64; mk <<= 1) v += __shfl_xor(v, mk);
    if (l == 0) {
        out[4 * NT]     = (ws[128] / (float)NT) * 0.001f;
        out[4 * NT + 1] = v * (float)(NE * NE) * 0.01f;
        out[4 * NT + 2] = ws[129] / (float)((size_t)NT * NE);
    }
}

extern "C" void kernel_launch(void* const* d_in, const int* in_sizes, int n_in,
                              void* d_out, int out_size, void* d_ws, size_t ws_size,
                              hipStream_t stream) {
    const float* x = (const float*)d_in[0];
    const float* W = (const float*)d_in[1];
    float* out = (float*)d_out;
    float* ws  = (float*)d_ws;

    const size_t need4 = (size_t)(SLAB2 + 4ull * NT * NE) * 4;
    if (ws_size >= need4) {
        hipLaunchKernelGGL(convert_w, dim3(128), dim3(256), 0, stream, W, ws);
        hipLaunchKernelGGL(pass1_ph, dim3(4 * 512), dim3(512), 0, stream, x, ws);
        hipLaunchKernelGGL(pass2, dim3(NT / 128), dim3(128), 0, stream,
                           ws, out, 4, SLAB2, NT / 128, 1);
    } else {
        hipMemsetAsync(ws, 0, 131 * sizeof(float), stream);
        int kq_bits = 2;
        if (ws_size < (SLAB_OFF + 4ull * NT * NE) * 4) kq_bits = 1;
        if (ws_size < (SLAB_OFF + 2ull * NT * NE) * 4) kq_bits = 0;
        const int kq = 1 << kq_bits;
        const int nchunk = (ND >> kq_bits) / BKD;
        hipLaunchKernelGGL(pass1_dbuf, dim3(256 * kq), dim3(256), 0, stream,
                           x, W, ws, kq_bits, nchunk);
        hipLaunchKernelGGL(pass2, dim3(NT / 128), dim3(128), 0, stream,
                           ws, out, kq, SLAB_OFF, NT / 128, 0);
        hipLaunchKernelGGL(finalize, dim3(1), dim3(64), 0, stream, ws, out);
    }
}

// Round 20
// 52.400 us; speedup vs baseline: 1.5341x; 1.5341x over previous
//
#include <hip/hip_runtime.h>
#include <math.h>

// ---------------------------------------------------------------------------
// Fused MoE top-2 router, MI355X (gfx950) — round 20 = R18 verbatim (best:
// 52.6us, absmax 0.0039). R19's phase-split regressed (80.4us) by violating
// the session invariant: plain register global loads get SUNK by hipcc
// (proven R8/R12/R13) -> serial latency chains. Design-space closure: any
// >=1KB x-granule staging needs >=96KB LDS/block at 64-token amortization ->
// 1 block/CU -> loses the cross-block overlap R14 relies on (R15 measured);
// 16-token blocks quadruple B-frag LDS traffic -> 40us LDS-bound. R18's
// point (256B granules, 64KB LDS, 2 blocks/CU, all-global_load_lds staging,
// bf16 hi/lo split MFMA) is the feasible optimum of this family.
// Pipeline: convert_w (+scalar zeroing) -> pass1_lds -> pass2 (+fused
// last-block finalize). 3 graph nodes.
// ---------------------------------------------------------------------------

#define NT 8192
#define ND 4096
#define NE 64
#define W_OFF 512         // float idx: wh (512KB)
#define WL_OFF (W_OFF + 131072)
#define SLAB2 (W_OFF + 262144)
#define BKD 64            // fallback chunk
#define SLAB_OFF 512      // fallback slab base

typedef float f32x4 __attribute__((ext_vector_type(4)));
typedef short s16x8 __attribute__((ext_vector_type(8)));

__device__ __forceinline__ void gload16(const float* g, float* l) {
    __builtin_amdgcn_global_load_lds(
        (const __attribute__((address_space(1))) void*)g,
        (__attribute__((address_space(3))) void*)l, 16, 0, 0);
}

// ---- W pre-convert: fp32 -> bf16 hi/lo, fragment-major, coalesced ---------
__global__ __launch_bounds__(256)
void convert_w(const float* __restrict__ W, float* __restrict__ ws)
{
    if (blockIdx.x == 0 && threadIdx.x < 131) ws[threadIdx.x] = 0.f;

    const int s = blockIdx.x * 256 + threadIdx.x;   // frag slot 0..32767
    const int sg  = s >> 8;          // kstep
    const int nt  = (s >> 6) & 3;    // n-tile
    const int kb  = (s >> 4) & 3;    // k-block (lane>>4)
    const int e15 = s & 15;
    const int e   = nt * 16 + e15;
    const int k0  = sg * 32 + kb * 8;
    const float* wr = W + (size_t)e * ND + k0;

    union { s16x8 v; ushort u[8]; } h, l;
    #pragma unroll
    for (int j = 0; j < 8; j++) {
        const float v = wr[j];
        const unsigned ub = __float_as_uint(v);
        h.u[j] = (ushort)(ub >> 16);
        const float lo = v - __uint_as_float(ub & 0xffff0000u);
        l.u[j] = (ushort)(__float_as_uint(lo) >> 16);
    }
    *(s16x8*)((ushort*)(ws + W_OFF) + (size_t)s * 8) = h.v;
    *(s16x8*)((ushort*)(ws + WL_OFF) + (size_t)s * 8) = l.v;
}

// ---- split + 6-term MFMA (validated R12/R14/R18) --------------------------
#define CMFMA(va, vb, bh0, bh1, bl0, bl1)                                    \
    {                                                                        \
        union { s16x8 v; ushort u[8]; } ah, al;                              \
        _Pragma("unroll")                                                    \
        for (int i = 0; i < 4; i++) {                                        \
            const unsigned u0 = __float_as_uint(va[i]);                      \
            ah.u[i] = (ushort)(u0 >> 16);                                    \
            const float l0 = va[i] - __uint_as_float(u0 & 0xffff0000u);      \
            al.u[i] = (ushort)(__float_as_uint(l0) >> 16);                   \
            const unsigned u1 = __float_as_uint(vb[i]);                      \
            ah.u[4 + i] = (ushort)(u1 >> 16);                                \
            const float l1 = vb[i] - __uint_as_float(u1 & 0xffff0000u);      \
            al.u[4 + i] = (ushort)(__float_as_uint(l1) >> 16);               \
        }                                                                    \
        acc0 = __builtin_amdgcn_mfma_f32_16x16x32_bf16(ah.v, bh0, acc0, 0,0,0);\
        acc1 = __builtin_amdgcn_mfma_f32_16x16x32_bf16(ah.v, bh1, acc1, 0,0,0);\
        acc0 = __builtin_amdgcn_mfma_f32_16x16x32_bf16(al.v, bh0, acc0, 0,0,0);\
        acc1 = __builtin_amdgcn_mfma_f32_16x16x32_bf16(al.v, bh1, acc1, 0,0,0);\
        acc0 = __builtin_amdgcn_mfma_f32_16x16x32_bf16(ah.v, bl0, acc0, 0,0,0);\
        acc1 = __builtin_amdgcn_mfma_f32_16x16x32_bf16(ah.v, bl1, acc1, 0,0,0);\
    }

// ---- primary: x+W both via global_load_lds, kq=4 (R14/R18 verbatim) -------
__global__ __launch_bounds__(512, 2)
void pass1_lds(const float* __restrict__ x, float* __restrict__ ws)
{
    __shared__ float  xbuf[2][4096];    // 2 x 16KB   x chunk (swizzled)
    __shared__ ushort wbuf[2][8192];    // 2 x 16KB   W frags [h:4096|l:4096]

    const int tid  = threadIdx.x;
    const int wv   = tid >> 6, lane = tid & 63;
    const int mt   = wv >> 1,  ng   = wv & 1;
    const int bq   = blockIdx.x >> 7;      // k-quarter 0..3
    const int tb   = blockIdx.x & 127;
    const int tok0 = tb * 64;
    const int ntg0 = ng * 2, ntg1 = ng * 2 + 1;
    const int k0   = bq << 10;

    const int t0 = tid >> 4, j0 = tid & 15;
    const int t1 = t0 + 32;
    const float* xg0 = x + (size_t)(tok0 + t0) * ND + k0 + ((j0 ^ (t0 & 7)) << 2);
    const float* xg1 = x + (size_t)(tok0 + t1) * ND + k0 + ((j0 ^ (t1 & 7)) << 2);
    const ushort* whg = (const ushort*)(ws + W_OFF);
    const ushort* wlg = (const ushort*)(ws + WL_OFF);

#define STAGE(bb, cc)                                                        \
    {                                                                        \
        gload16(xg0 + (cc) * 64, &xbuf[bb][tid * 4]);                        \
        gload16(xg1 + (cc) * 64, &xbuf[bb][2048 + tid * 4]);                 \
        const size_t cb = ((size_t)(bq * 32 + (cc) * 2) * 4096)              \
                        + (size_t)tid * 16;                                  \
        gload16((const float*)((const char*)whg + cb),                       \
                (float*)&wbuf[bb][(size_t)tid * 8]);                         \
        gload16((const float*)((const char*)wlg + cb),                       \
                (float*)&wbuf[bb][4096 + (size_t)tid * 8]);                  \
    }

    f32x4 acc0 = {0.f, 0.f, 0.f, 0.f};
    f32x4 acc1 = {0.f, 0.f, 0.f, 0.f};

    const int tl  = mt * 16 + (lane & 15);   // token row in x LDS
    const int swz = lane & 7;                // == tl & 7
    const int kb4 = (lane >> 4) * 2;         // 16B slot base within kstep

    STAGE(0, 0);
    __syncthreads();

    int b = 0;
    #pragma unroll 1
    for (int c = 0; c < 16; ++c) {
        if (c + 1 < 16) STAGE(b ^ 1, c + 1);
        const char*   xb = (const char*)xbuf[b] + tl * 256;
        const ushort* wb = wbuf[b];
        #pragma unroll
        for (int ks = 0; ks < 2; ++ks) {
            const f32x4 va = *(const f32x4*)(xb + (((ks * 8 + kb4)     ^ swz) << 4));
            const f32x4 vb = *(const f32x4*)(xb + (((ks * 8 + kb4 + 1) ^ swz) << 4));
            const s16x8 bh0 = *(const s16x8*)(wb + ((ks * 4 + ntg0) << 9) + lane * 8);
            const s16x8 bh1 = *(const s16x8*)(wb + ((ks * 4 + ntg1) << 9) + lane * 8);
            const s16x8 bl0 = *(const s16x8*)(wb + 4096 + ((ks * 4 + ntg0) << 9) + lane * 8);
            const s16x8 bl1 = *(const s16x8*)(wb + 4096 + ((ks * 4 + ntg1) << 9) + lane * 8);
            CMFMA(va, vb, bh0, bh1, bl0, bl1);
        }
        __syncthreads();
        b ^= 1;
    }
#undef STAGE

    float* slab = ws + SLAB2 + (size_t)bq * NT * NE;
    const int er = (lane >> 4) * 4;
    #pragma unroll
    for (int r = 0; r < 4; r++) {
        const int token = tok0 + mt * 16 + er + r;
        slab[(size_t)token * NE + ntg0 * 16 + (lane & 15)] = acc0[r];
        slab[(size_t)token * NE + ntg1 * 16 + (lane & 15)] = acc1[r];
    }
}

// ---- fallback: R8 VALU double-buffer path (only if ws tiny) ---------------
#define LOADX(dst, off)                                                      \
    {                                                                        \
        _Pragma("unroll")                                                    \
        for (int t = 0; t < 8; t++)                                          \
            dst[t] = *reinterpret_cast<const float4*>(                       \
                xp + (size_t)t * ND + (off));                                \
    }
#define COMP(xv, wptr, wstride)                                              \
    {                                                                        \
        float4 wvv[8];                                                       \
        _Pragma("unroll")                                                    \
        for (int e = 0; e < 8; e++)                                          \
            wvv[e] = *reinterpret_cast<const float4*>((wptr) + e * (wstride));\
        _Pragma("unroll")                                                    \
        for (int e = 0; e < 8; e++) {                                        \
            _Pragma("unroll")                                                \
            for (int t = 0; t < 8; t++) {                                    \
                float a = acc[t][e];                                         \
                a = fmaf(xv[t].x, wvv[e].x, a);                              \
                a = fmaf(xv[t].y, wvv[e].y, a);                              \
                a = fmaf(xv[t].z, wvv[e].z, a);                              \
                a = fmaf(xv[t].w, wvv[e].w, a);                              \
                acc[t][e] = a;                                               \
            }                                                                \
        }                                                                    \
    }

__global__ __launch_bounds__(256, 2)
void pass1_dbuf(const float* __restrict__ x, const float* __restrict__ W,
                float* __restrict__ ws, int kq_bits, int nchunk)
{
    __shared__ float wbuf[2][NE * BKD];
    const int tid  = threadIdx.x;
    const int wave = tid >> 6;
    const int lane = tid & 63;
    const int eg   = lane >> 3;
    const int ks   = lane & 7;
    const int bq   = blockIdx.x >> 8;
    const int tb   = blockIdx.x & 255;
    const int tok0 = tb * 32 + wave * 8;
    const int k0   = bq * (ND >> kq_bits);

    float acc[8][8];
    #pragma unroll
    for (int t = 0; t < 8; t++)
        #pragma unroll
        for (int e = 0; e < 8; e++) acc[t][e] = 0.f;

    const float* xp = x + (size_t)tok0 * ND + k0 + ks * 4;
    #pragma unroll
    for (int r = 0; r < 4; r++) {
        int s = r * 256 + tid;
        gload16(W + (size_t)(s >> 4) * ND + k0 + (s & 15) * 4, &wbuf[0][s << 2]);
    }
    float4 xa[8], xb[8];
    LOADX(xa, 0);
    __syncthreads();

    #pragma unroll 1
    for (int c = 0; c < nchunk; ++c) {
        const int b = c & 1;
        if (c + 1 < nchunk) {
            const int koff = k0 + (c + 1) * BKD;
            #pragma unroll
            for (int r = 0; r < 4; r++) {
                int s = r * 256 + tid;
                gload16(W + (size_t)(s >> 4) * ND + koff + (s & 15) * 4,
                        &wbuf[b ^ 1][s << 2]);
            }
        }
        LOADX(xb, c * BKD + 32);
        COMP(xa, &wbuf[b][(eg * 8) * BKD + ks * 4], BKD);
        if (c + 1 < nchunk) LOADX(xa, (c + 1) * BKD);
        COMP(xb, &wbuf[b][(eg * 8) * BKD + 32 + ks * 4], BKD);
        __syncthreads();
    }

    #pragma unroll
    for (int t = 0; t < 8; t++)
        #pragma unroll
        for (int e = 0; e < 8; e++) {
            float v = acc[t][e];
            v += __shfl_xor(v, 1);
            v += __shfl_xor(v, 2);
            v += __shfl_xor(v, 4);
            acc[t][e] = v;
        }
    float* slab = ws + SLAB_OFF + ((size_t)bq * NT + tok0) * NE;
    #pragma unroll
    for (int t = 0; t < 8; t++) {
        if (ks == t) {
            *reinterpret_cast<float4*>(slab + (size_t)t * NE + eg * 8) =
                make_float4(acc[t][0], acc[t][1], acc[t][2], acc[t][3]);
            *reinterpret_cast<float4*>(slab + (size_t)t * NE + eg * 8 + 4) =
                make_float4(acc[t][4], acc[t][5], acc[t][6], acc[t][7]);
        }
    }
}

// ---- pass2 (R18 verbatim) + fused last-block finalize ----------------------
__global__ __launch_bounds__(128)
void pass2(float* __restrict__ ws, float* __restrict__ out, int kq,
           int slab_base, int nblocks, int do_fuse)
{
    __shared__ float imp_s[NE];
    __shared__ float load_s[NE];
    __shared__ int lastflag;
    const int tid  = threadIdx.x;
    const int lane = tid & 63;
    if (tid < NE) { imp_s[tid] = 0.f; load_s[tid] = 0.f; }
    __syncthreads();

    const int tok = blockIdx.x * 128 + tid;
    float lgv[NE];
    {
        const float* p0 = ws + slab_base + (size_t)tok * NE;
        #pragma unroll
        for (int e4 = 0; e4 < 16; e4++) {
            float4 v = *reinterpret_cast<const float4*>(p0 + e4 * 4);
            lgv[e4*4+0] = v.x; lgv[e4*4+1] = v.y;
            lgv[e4*4+2] = v.z; lgv[e4*4+3] = v.w;
        }
        for (int q = 1; q < kq; q++) {
            const float* pq = ws + slab_base + ((size_t)q * NT + tok) * NE;
            #pragma unroll
            for (int e4 = 0; e4 < 16; e4++) {
                float4 v = *reinterpret_cast<const float4*>(pq + e4 * 4);
                lgv[e4*4+0] += v.x; lgv[e4*4+1] += v.y;
                lgv[e4*4+2] += v.z; lgv[e4*4+3] += v.w;
            }
        }
    }

    float m = -3.0e38f;
    #pragma unroll
    for (int e = 0; e < NE; e++) m = fmaxf(m, lgv[e]);
    float se = 0.f, ssum = 0.f;
    #pragma unroll
    for (int e = 0; e < NE; e++) { ssum += lgv[e]; se += __expf(lgv[e] - m); }
    const float lse = m + __logf(se);
    const float inv = 1.f / se;

    #pragma unroll
    for (int e = 0; e < NE; e++) lgv[e] = __expf(lgv[e] - m) * inv;

    float v1 = -3.0e38f, v2 = -3.0e38f;
    int   i1 = 0, i2 = 0;
    #pragma unroll
    for (int e = 0; e < NE; e++) {
        const float v = lgv[e];
        if (v > v1)      { v2 = v1; i2 = i1; v1 = v; i1 = e; }
        else if (v > v2) { v2 = v;  i2 = e; }
    }
    const float dn = fmaxf(v1 + v2, 1e-9f);

    out[2 * tok]              = (float)i1;
    out[2 * tok + 1]          = (float)i2;
    out[2 * NT + 2 * tok]     = v1 / dn;
    out[2 * NT + 2 * tok + 1] = v2 / dn;
    atomicAdd(&load_s[i1], 1.0f);

    float zv = lse * lse, sv = ssum;
    #pragma unroll
    for (int mk = 1; mk < 64; mk <<= 1) {
        zv += __shfl_xor(zv, mk);
        sv += __shfl_xor(sv, mk);
    }
    if (lane == 0) { atomicAdd(&ws[128], zv); atomicAdd(&ws[129], sv); }

    float impacc = 0.f;
    #pragma unroll
    for (int e = 0; e < NE; e++) {
        float v = lgv[e];
        #pragma unroll
        for (int mk = 1; mk < 64; mk <<= 1) v += __shfl_xor(v, mk);
        if (lane == e) impacc = v;
    }
    atomicAdd(&imp_s[lane], impacc);

    __syncthreads();
    if (tid < NE) {
        atomicAdd(&ws[tid], imp_s[tid]);
        atomicAdd(&ws[NE + tid], load_s[tid]);
    }

    if (!do_fuse) return;

    __threadfence();
    if (tid == 0) {
        const int old = atomicAdd((int*)(ws + 130), 1);
        lastflag = (old == nblocks - 1);
    }
    __syncthreads();
    if (lastflag && tid < 64) {
        const float imp = atomicAdd(&ws[tid], 0.f);
        const float ld  = atomicAdd(&ws[NE + tid], 0.f);
        float is = imp, ls = ld;
        #pragma unroll
        for (int mk = 1; mk < 64; mk <<= 1) {
            is += __shfl_xor(is, mk);
            ls += __shfl_xor(ls, mk);
        }
        float v = (imp / fmaxf(is, 1e-9f)) * (ld / fmaxf(ls, 1e-9f));
        #pragma unroll
        for (int mk = 1; mk < 64; mk <<= 1) v += __shfl_xor(v, mk);
        if (tid == 0) {
            const float zz = atomicAdd(&ws[128], 0.f);
            const float ss = atomicAdd(&ws[129], 0.f);
            out[4 * NT]     = (zz / (float)NT) * 0.001f;
            out[4 * NT + 1] = v * (float)(NE * NE) * 0.01f;
            out[4 * NT + 2] = ss / (float)((size_t)NT * NE);
        }
    }
}

__global__ void finalize(const float* __restrict__ ws, float* __restrict__ out)
{
    const int l = threadIdx.x;
    const float imp = ws[l];
    const float ld  = ws[NE + l];
    float is = imp, ls = ld;
    #pragma unroll
    for (int mk = 1; mk < 64; mk <<= 1) { is += __shfl_xor(is, mk); ls += __shfl_xor(ls, mk); }
    float v = (imp / fmaxf(is, 1e-9f)) * (ld / fmaxf(ls, 1e-9f));
    #pragma unroll
    for (int mk = 1; mk < 64; mk <<= 1) v += __shfl_xor(v, mk);
    if (l == 0) {
        out[4 * NT]     = (ws[128] / (float)NT) * 0.001f;
        out[4 * NT + 1] = v * (float)(NE * NE) * 0.01f;
        out[4 * NT + 2] = ws[129] / (float)((size_t)NT * NE);
    }
}

extern "C" void kernel_launch(void* const* d_in, const int* in_sizes, int n_in,
                              void* d_out, int out_size, void* d_ws, size_t ws_size,
                              hipStream_t stream) {
    const float* x = (const float*)d_in[0];
    const float* W = (const float*)d_in[1];
    float* out = (float*)d_out;
    float* ws  = (float*)d_ws;

    const size_t need4 = (size_t)(SLAB2 + 4ull * NT * NE) * 4;
    if (ws_size >= need4) {
        hipLaunchKernelGGL(convert_w, dim3(128), dim3(256), 0, stream, W, ws);
        hipLaunchKernelGGL(pass1_lds, dim3(4 * 128), dim3(512), 0, stream, x, ws);
        hipLaunchKernelGGL(pass2, dim3(NT / 128), dim3(128), 0, stream,
                           ws, out, 4, SLAB2, NT / 128, 1);
    } else {
        hipMemsetAsync(ws, 0, 131 * sizeof(float), stream);
        int kq_bits = 2;
        if (ws_size < (SLAB_OFF + 4ull * NT * NE) * 4) kq_bits = 1;
        if (ws_size < (SLAB_OFF + 2ull * NT * NE) * 4) kq_bits = 0;
        const int kq = 1 << kq_bits;
        const int nchunk = (ND >> kq_bits) / BKD;
        hipLaunchKernelGGL(pass1_dbuf, dim3(256 * kq), dim3(256), 0, stream,
                           x, W, ws, kq_bits, nchunk);
        hipLaunchKernelGGL(pass2, dim3(NT / 128), dim3(128), 0, stream,
                           ws, out, kq, SLAB_OFF, NT / 128, 0);
        hipLaunchKernelGGL(finalize, dim3(1), dim3(64), 0, stream, ws, out);
    }
}